// Round 12
// baseline (132.635 us; speedup 1.0000x reference)
//
#include <hip/hip_runtime.h>

#define D 64
#define SCAN_CHUNK 1024

typedef short bf16x8 __attribute__((ext_vector_type(8)));
typedef float f32x4 __attribute__((ext_vector_type(4)));

__device__ __forceinline__ short f2bf(float x) {
  unsigned u = __builtin_bit_cast(unsigned, x);
  u = u + 0x7FFFu + ((u >> 16) & 1u);   // round-to-nearest-even
  return (short)(u >> 16);
}
__device__ __forceinline__ float bf2f(unsigned short u) {
  unsigned v = ((unsigned)u) << 16;
  return __builtin_bit_cast(float, v);
}

// ---------------- rel kernel: R2(bf16) = rel_emb @ Wf^T ; rel_out = rel_emb @ Wrel^T
// Also zeroes cnt (hist target; stream order guarantees done before k_hist).
__global__ __launch_bounds__(256) void rel_kernel(
    const float* __restrict__ rel_emb,
    const float* __restrict__ W_f,
    const float* __restrict__ W_rel,
    unsigned short* __restrict__ R2,
    float* __restrict__ rel_out,
    int n_rel,
    int4* __restrict__ cz, int ncz4) {
  {
    int i = blockIdx.x * blockDim.x + threadIdx.x;
    int stride = gridDim.x * blockDim.x;
    int4 z = {0, 0, 0, 0};
    for (; i < ncz4; i += stride) cz[i] = z;
  }
  __shared__ float WtF[D][D];
  __shared__ float WtR[D][D];
  int tid = threadIdx.x;
  for (int idx = tid; idx < D * D; idx += 256) {
    int j = idx >> 6, k = idx & 63;
    WtF[k][j] = W_f[idx];
    WtR[k][j] = W_rel[idx];
  }
  __syncthreads();
  int lane = tid & 63, wave = tid >> 6;
  for (int r = blockIdx.x * 4 + wave; r < n_rel; r += gridDim.x * 4) {
    const float4* a = (const float4*)(rel_emb + (size_t)r * D);
    float accR = 0.f, accO = 0.f;
#pragma unroll
    for (int k4 = 0; k4 < 16; ++k4) {
      float4 av = a[k4];
      int k = k4 * 4;
      accR += av.x * WtF[k][lane] + av.y * WtF[k + 1][lane] +
              av.z * WtF[k + 2][lane] + av.w * WtF[k + 3][lane];
      accO += av.x * WtR[k][lane] + av.y * WtR[k + 1][lane] +
              av.z * WtR[k + 2][lane] + av.w * WtR[k + 3][lane];
    }
    R2[(size_t)r * D + lane] = (unsigned short)f2bf(accR);
    rel_out[(size_t)r * D + lane] = accO;
  }
}

// ---------------- node GEMM via MFMA (bf16 inputs, f32 accum):
// out = nf @ Ws^T + bias (f32) ; X2 = nf @ Wf^T (stored bf16)
__global__ __launch_bounds__(256) void node_mfma(
    const float* __restrict__ nf,
    const float* __restrict__ W_self,
    const float* __restrict__ W_f,
    const float* __restrict__ bias,
    float* __restrict__ out,
    unsigned short* __restrict__ X2,
    int n_nodes) {
  int tid = threadIdx.x;
  int lane = tid & 63;
  int l15 = lane & 15;
  int kg = lane >> 4;

  bf16x8 bS[4][2], bF[4][2];
#pragma unroll
  for (int q = 0; q < 4; ++q) {
#pragma unroll
    for (int h = 0; h < 2; ++h) {
      const float* ps = W_self + (size_t)(q * 16 + l15) * D + h * 32 + kg * 8;
      const float* pf = W_f + (size_t)(q * 16 + l15) * D + h * 32 + kg * 8;
      float4 s0 = *(const float4*)ps, s1 = *(const float4*)(ps + 4);
      float4 f0 = *(const float4*)pf, f1 = *(const float4*)(pf + 4);
      bf16x8 vs, vf;
      vs[0] = f2bf(s0.x); vs[1] = f2bf(s0.y); vs[2] = f2bf(s0.z); vs[3] = f2bf(s0.w);
      vs[4] = f2bf(s1.x); vs[5] = f2bf(s1.y); vs[6] = f2bf(s1.z); vs[7] = f2bf(s1.w);
      vf[0] = f2bf(f0.x); vf[1] = f2bf(f0.y); vf[2] = f2bf(f0.z); vf[3] = f2bf(f0.w);
      vf[4] = f2bf(f1.x); vf[5] = f2bf(f1.y); vf[6] = f2bf(f1.z); vf[7] = f2bf(f1.w);
      bS[q][h] = vs;
      bF[q][h] = vf;
    }
  }
  float bq[4];
#pragma unroll
  for (int q = 0; q < 4; ++q) bq[q] = bias[q * 16 + l15];

  int wave = (int)((blockIdx.x * blockDim.x + tid) >> 6);
  int n_waves = (int)((gridDim.x * blockDim.x) >> 6);
  int ntiles = (n_nodes + 15) >> 4;

  for (int t = wave; t < ntiles; t += n_waves) {
    int base = t << 4;
    int arow = base + l15;
    if (arow >= n_nodes) arow = n_nodes - 1;
    const float* ap = nf + (size_t)arow * D + kg * 8;
    float4 a00 = *(const float4*)ap;
    float4 a01 = *(const float4*)(ap + 4);
    float4 a10 = *(const float4*)(ap + 32);
    float4 a11 = *(const float4*)(ap + 36);
    bf16x8 af0, af1;
    af0[0] = f2bf(a00.x); af0[1] = f2bf(a00.y); af0[2] = f2bf(a00.z); af0[3] = f2bf(a00.w);
    af0[4] = f2bf(a01.x); af0[5] = f2bf(a01.y); af0[6] = f2bf(a01.z); af0[7] = f2bf(a01.w);
    af1[0] = f2bf(a10.x); af1[1] = f2bf(a10.y); af1[2] = f2bf(a10.z); af1[3] = f2bf(a10.w);
    af1[4] = f2bf(a11.x); af1[5] = f2bf(a11.y); af1[6] = f2bf(a11.z); af1[7] = f2bf(a11.w);

    bool full = (base + 16 <= n_nodes);
#pragma unroll
    for (int q = 0; q < 4; ++q) {
      f32x4 accS = {0.f, 0.f, 0.f, 0.f};
      f32x4 accF = {0.f, 0.f, 0.f, 0.f};
      accS = __builtin_amdgcn_mfma_f32_16x16x32_bf16(af0, bS[q][0], accS, 0, 0, 0);
      accS = __builtin_amdgcn_mfma_f32_16x16x32_bf16(af1, bS[q][1], accS, 0, 0, 0);
      accF = __builtin_amdgcn_mfma_f32_16x16x32_bf16(af0, bF[q][0], accF, 0, 0, 0);
      accF = __builtin_amdgcn_mfma_f32_16x16x32_bf16(af1, bF[q][1], accF, 0, 0, 0);
      int col = q * 16 + l15;
      int row0 = base + kg * 4;
      size_t o = (size_t)row0 * D + col;
      if (full) {
#pragma unroll
        for (int r = 0; r < 4; ++r) {
          out[o + (size_t)r * D] = accS[r] + bq[q];
          X2[o + (size_t)r * D] = (unsigned short)f2bf(accF[r]);
        }
      } else {
#pragma unroll
        for (int r = 0; r < 4; ++r) {
          if (row0 + r < n_nodes) {
            out[o + (size_t)r * D] = accS[r] + bq[q];
            X2[o + (size_t)r * D] = (unsigned short)f2bf(accF[r]);
          }
        }
      }
    }
  }
}

// ---------------- hist: int4-vectorized (4 edges/thread/iter)
__global__ __launch_bounds__(256) void k_hist(
    const int* __restrict__ dst, const int* __restrict__ dir,
    int* __restrict__ cnt, int n_edges) {
  int i = blockIdx.x * blockDim.x + threadIdx.x;
  int stride = gridDim.x * blockDim.x;
  int nv = n_edges >> 2;
  const int4* d4 = (const int4*)dst;
  const int4* r4 = (const int4*)dir;
  for (int v = i; v < nv; v += stride) {
    int4 d = d4[v];
    int4 r = r4[v];
    if (r.x == 0) atomicAdd(&cnt[d.x], 1);
    if (r.y == 0) atomicAdd(&cnt[d.y], 1);
    if (r.z == 0) atomicAdd(&cnt[d.z], 1);
    if (r.w == 0) atomicAdd(&cnt[d.w], 1);
  }
  for (int e = (nv << 2) + i; e < n_edges; e += stride)
    if (dir[e] == 0) atomicAdd(&cnt[dst[e]], 1);
}

// ---------------- fused scan: cursor2[i] = exclusive_prefix(cnt)[i]
// Race-free fusion of sums+scan: cnt is READ-ONLY here; each block
// redundantly reduces preceding chunks (coalesced int4) then scans its own.
__global__ __launch_bounds__(256) void k_scan_fused(
    const int* __restrict__ cnt, int* __restrict__ cursor2, int n) {
  __shared__ int wsum[4];
  __shared__ int off_s;
  int b = blockIdx.x, t = threadIdx.x;
  int lane = t & 63, wave = t >> 6;

  // off = sum of cnt[0 .. b*SCAN_CHUNK)
  {
    int v = 0;
    const int4* c4 = (const int4*)cnt;
    int lim4 = (b * SCAN_CHUNK) >> 2;          // SCAN_CHUNK%4==0
    for (int i = t; i < lim4; i += 256) {
      int4 c = c4[i];
      v += c.x + c.y + c.z + c.w;
    }
    for (int o = 32; o; o >>= 1) v += __shfl_down(v, o);
    if (lane == 0) wsum[wave] = v;
    __syncthreads();
    if (t == 0) off_s = wsum[0] + wsum[1] + wsum[2] + wsum[3];
    __syncthreads();
  }
  __syncthreads();

  int i0 = b * SCAN_CHUNK + t * 4;
  int c0 = (i0 + 0 < n) ? cnt[i0 + 0] : 0;
  int c1 = (i0 + 1 < n) ? cnt[i0 + 1] : 0;
  int c2 = (i0 + 2 < n) ? cnt[i0 + 2] : 0;
  int c3 = (i0 + 3 < n) ? cnt[i0 + 3] : 0;
  int s = c0 + c1 + c2 + c3;
  int inc = s;
  for (int d = 1; d < 64; d <<= 1) {
    int v = __shfl_up(inc, d);
    if (lane >= d) inc += v;
  }
  if (lane == 63) wsum[wave] = inc;
  __syncthreads();
  int wbase = 0;
  if (wave > 0) wbase += wsum[0];
  if (wave > 1) wbase += wsum[1];
  if (wave > 2) wbase += wsum[2];
  int ex = off_s + wbase + inc - s;
  if (i0 + 0 < n) cursor2[i0 + 0] = ex;
  if (i0 + 1 < n) cursor2[i0 + 1] = ex + c0;
  if (i0 + 2 < n) cursor2[i0 + 2] = ex + c0 + c1;
  if (i0 + 3 < n) cursor2[i0 + 3] = ex + c0 + c1 + c2;
}

// ---------------- scatter packed (src<<8)|etype, int4-vectorized
__global__ __launch_bounds__(256) void k_scatter_packed(
    const int* __restrict__ src, const int* __restrict__ dst,
    const int* __restrict__ et, const int* __restrict__ dir,
    int* __restrict__ cursor, int* __restrict__ perm, int n_edges) {
  int i = blockIdx.x * blockDim.x + threadIdx.x;
  int stride = gridDim.x * blockDim.x;
  int nv = n_edges >> 2;
  const int4* s4 = (const int4*)src;
  const int4* d4 = (const int4*)dst;
  const int4* t4 = (const int4*)et;
  const int4* r4 = (const int4*)dir;
  for (int v = i; v < nv; v += stride) {
    int4 s = s4[v];
    int4 d = d4[v];
    int4 tt = t4[v];
    int4 r = r4[v];
    if (r.x == 0) perm[atomicAdd(&cursor[d.x], 1)] = (s.x << 8) | tt.x;
    if (r.y == 0) perm[atomicAdd(&cursor[d.y], 1)] = (s.y << 8) | tt.y;
    if (r.z == 0) perm[atomicAdd(&cursor[d.z], 1)] = (s.z << 8) | tt.z;
    if (r.w == 0) perm[atomicAdd(&cursor[d.w], 1)] = (s.w << 8) | tt.w;
  }
  for (int e = (nv << 2) + i; e < n_edges; e += stride)
    if (dir[e] == 0) {
      int pos = atomicAdd(&cursor[dst[e]], 1);
      perm[pos] = (src[e] << 8) | et[e];
    }
}

// ---------------- gather: out[n] += sum_{e in bucket(n)} X2[src[e]] - R2[et[e]]
__global__ __launch_bounds__(256) void k_gather(
    const int* __restrict__ cursor, const int* __restrict__ perm,
    const unsigned short* __restrict__ X2, const unsigned short* __restrict__ R2,
    float* __restrict__ out, int n_nodes) {
  int lane = threadIdx.x & 63;
  int wave_id = (int)((blockIdx.x * blockDim.x + threadIdx.x) >> 6);
  int n_waves = (int)((gridDim.x * blockDim.x) >> 6);
  for (int node = wave_id; node < n_nodes; node += n_waves) {
    int end = cursor[node];
    int beg = (node == 0) ? 0 : cursor[node - 1];
    if (end <= beg) continue;
    float acc = 0.f;
    int k = beg;
    for (; k + 3 < end; k += 4) {
      int p0 = perm[k], p1 = perm[k + 1], p2 = perm[k + 2], p3 = perm[k + 3];
      float a0 = bf2f(X2[(size_t)(p0 >> 8) * D + lane]) - bf2f(R2[(size_t)(p0 & 255) * D + lane]);
      float a1 = bf2f(X2[(size_t)(p1 >> 8) * D + lane]) - bf2f(R2[(size_t)(p1 & 255) * D + lane]);
      float a2 = bf2f(X2[(size_t)(p2 >> 8) * D + lane]) - bf2f(R2[(size_t)(p2 & 255) * D + lane]);
      float a3 = bf2f(X2[(size_t)(p3 >> 8) * D + lane]) - bf2f(R2[(size_t)(p3 & 255) * D + lane]);
      acc += (a0 + a1) + (a2 + a3);
    }
    if (k + 1 < end) {
      int p0 = perm[k], p1 = perm[k + 1];
      acc += bf2f(X2[(size_t)(p0 >> 8) * D + lane]) - bf2f(R2[(size_t)(p0 & 255) * D + lane]);
      acc += bf2f(X2[(size_t)(p1 >> 8) * D + lane]) - bf2f(R2[(size_t)(p1 & 255) * D + lane]);
      k += 2;
    }
    if (k < end) {
      int p = perm[k];
      acc += bf2f(X2[(size_t)(p >> 8) * D + lane]) - bf2f(R2[(size_t)(p & 255) * D + lane]);
    }
    out[(size_t)node * D + lane] += acc;
  }
}

// ---------------- fallback edge kernel (atomic, bf16 X/R) ----------------
__global__ __launch_bounds__(256) void edge_atomic(
    const int* __restrict__ src, const int* __restrict__ dst,
    const int* __restrict__ et, const int* __restrict__ dir,
    const unsigned short* __restrict__ X2, const unsigned short* __restrict__ R2,
    float* __restrict__ out, int n_edges) {
  int lane = threadIdx.x & 63;
  long long wave_id = ((long long)blockIdx.x * blockDim.x + threadIdx.x) >> 6;
  long long n_waves = ((long long)gridDim.x * blockDim.x) >> 6;
  for (long long base = wave_id * 64; base < n_edges; base += n_waves * 64) {
    int e = (int)base + lane;
    int s_l = 0, d_l = 0, t_l = 0, dir_l = 1;
    if (e < n_edges) {
      s_l = src[e]; d_l = dst[e]; t_l = et[e]; dir_l = dir[e];
    }
    int cnt = min(64, n_edges - (int)base);
    for (int i = 0; i < cnt; ++i) {
      int dir_i = __shfl(dir_l, i);
      if (dir_i != 0) continue;
      int s_i = __shfl(s_l, i);
      int t_i = __shfl(t_l, i);
      int d_i = __shfl(d_l, i);
      float val = bf2f(X2[(size_t)s_i * D + lane]) - bf2f(R2[(size_t)t_i * D + lane]);
      atomicAdd(&out[(size_t)d_i * D + lane], val);
    }
  }
}

extern "C" void kernel_launch(void* const* d_in, const int* in_sizes, int n_in,
                              void* d_out, int out_size, void* d_ws, size_t ws_size,
                              hipStream_t stream) {
  const float* node_feat = (const float*)d_in[0];
  const float* rel_emb   = (const float*)d_in[1];
  const int*   src       = (const int*)d_in[2];
  const int*   dst       = (const int*)d_in[3];
  const int*   etype     = (const int*)d_in[4];
  const int*   direction = (const int*)d_in[5];
  const float* W_self    = (const float*)d_in[6];
  const float* W_forward = (const float*)d_in[7];
  // d_in[8] = W_backward (unused: backward edges contribute zero)
  const float* W_rel     = (const float*)d_in[9];
  const float* bias      = (const float*)d_in[10];

  int n_nodes = in_sizes[0] / D;
  int n_rel   = in_sizes[1] / D;
  int n_edges = in_sizes[2];

  float* out     = (float*)d_out;
  float* rel_out = out + (size_t)n_nodes * D;

  // ws layout: X2(bf16), R2(bf16), cnt, cursor2, perm
  char* ws = (char*)d_ws;
  size_t offX = 0;
  size_t offR = offX + (size_t)n_nodes * D * 2;
  size_t offCnt = (offR + (size_t)n_rel * D * 2 + 15) & ~(size_t)15;
  size_t offCur2 = offCnt + (((size_t)n_nodes * 4 + 15) & ~(size_t)15);
  size_t offPerm = offCur2 + (((size_t)n_nodes * 4 + 15) & ~(size_t)15);
  size_t need = offPerm + (size_t)n_edges * 4;

  unsigned short* X2 = (unsigned short*)(ws + offX);
  unsigned short* R2 = (unsigned short*)(ws + offR);
  int* cnt = (int*)(ws + offCnt);
  int* cursor2 = (int*)(ws + offCur2);
  int* perm = (int*)(ws + offPerm);

  bool packed_ok = (n_rel <= 256) && (n_nodes < (1 << 23));
  bool csr = (ws_size >= need) && packed_ok;
  int ncz4 = csr ? (n_nodes + 3) / 4 : 0;

  // 1) R2(bf16) + rel_out (+ cnt zero, folded)
  rel_kernel<<<64, 256, 0, stream>>>(rel_emb, W_forward, W_rel, R2, rel_out,
                                     n_rel, (int4*)cnt, ncz4);

  // 2) out = nf@Ws^T + bias ; X2 = nf@Wf^T (bf16) via MFMA
  node_mfma<<<512, 256, 0, stream>>>(node_feat, W_self, W_forward, bias,
                                     out, X2, n_nodes);

  if (csr) {
    int nblk = (n_nodes + SCAN_CHUNK - 1) / SCAN_CHUNK;
    k_hist<<<1024, 256, 0, stream>>>(dst, direction, cnt, n_edges);
    k_scan_fused<<<nblk, 256, 0, stream>>>(cnt, cursor2, n_nodes);
    k_scatter_packed<<<1024, 256, 0, stream>>>(src, dst, etype, direction,
                                               cursor2, perm, n_edges);
    k_gather<<<4096, 256, 0, stream>>>(cursor2, perm, X2, R2, out, n_nodes);
  } else {
    edge_atomic<<<2048, 256, 0, stream>>>(src, dst, etype, direction, X2, R2,
                                          out, n_edges);
  }
}

// Round 13
// 114.355 us; speedup vs baseline: 1.1599x; 1.1599x over previous
//
#include <hip/hip_runtime.h>

#define D 64
#define SCAN_CHUNK 1024

typedef short bf16x8 __attribute__((ext_vector_type(8)));
typedef float f32x4 __attribute__((ext_vector_type(4)));

__device__ __forceinline__ short f2bf(float x) {
  unsigned u = __builtin_bit_cast(unsigned, x);
  u = u + 0x7FFFu + ((u >> 16) & 1u);   // round-to-nearest-even
  return (short)(u >> 16);
}
__device__ __forceinline__ float bf2f(unsigned short u) {
  unsigned v = ((unsigned)u) << 16;
  return __builtin_bit_cast(float, v);
}

// ---------------- rel kernel: R2(bf16) = rel_emb @ Wf^T ; rel_out = rel_emb @ Wrel^T
// Also zeroes cnt (hist target; stream order guarantees done before node_hist).
__global__ __launch_bounds__(256) void rel_kernel(
    const float* __restrict__ rel_emb,
    const float* __restrict__ W_f,
    const float* __restrict__ W_rel,
    unsigned short* __restrict__ R2,
    float* __restrict__ rel_out,
    int n_rel,
    int4* __restrict__ cz, int ncz4) {
  {
    int i = blockIdx.x * blockDim.x + threadIdx.x;
    int stride = gridDim.x * blockDim.x;
    int4 z = {0, 0, 0, 0};
    for (; i < ncz4; i += stride) cz[i] = z;
  }
  __shared__ float WtF[D][D];
  __shared__ float WtR[D][D];
  int tid = threadIdx.x;
  for (int idx = tid; idx < D * D; idx += 256) {
    int j = idx >> 6, k = idx & 63;
    WtF[k][j] = W_f[idx];
    WtR[k][j] = W_rel[idx];
  }
  __syncthreads();
  int lane = tid & 63, wave = tid >> 6;
  for (int r = blockIdx.x * 4 + wave; r < n_rel; r += gridDim.x * 4) {
    const float4* a = (const float4*)(rel_emb + (size_t)r * D);
    float accR = 0.f, accO = 0.f;
#pragma unroll
    for (int k4 = 0; k4 < 16; ++k4) {
      float4 av = a[k4];
      int k = k4 * 4;
      accR += av.x * WtF[k][lane] + av.y * WtF[k + 1][lane] +
              av.z * WtF[k + 2][lane] + av.w * WtF[k + 3][lane];
      accO += av.x * WtR[k][lane] + av.y * WtR[k + 1][lane] +
              av.z * WtR[k + 2][lane] + av.w * WtR[k + 3][lane];
    }
    R2[(size_t)r * D + lane] = (unsigned short)f2bf(accR);
    rel_out[(size_t)r * D + lane] = accO;
  }
}

// ---------------- fused node GEMM (MFMA) + hist (heterogeneous block ranges)
// blocks [0, nodeBlocks): out = nf@Ws^T + bias (f32); X2 = nf@Wf^T (bf16)
// blocks [nodeBlocks, nodeBlocks+histBlocks): cnt histogram of forward dst
// hist needs cnt zeroed -- done by rel_kernel (same stream, earlier launch).
__global__ __launch_bounds__(256) void node_hist(
    const float* __restrict__ nf,
    const float* __restrict__ W_self,
    const float* __restrict__ W_f,
    const float* __restrict__ bias,
    float* __restrict__ out,
    unsigned short* __restrict__ X2,
    int n_nodes,
    const int* __restrict__ dst, const int* __restrict__ dir,
    int* __restrict__ cnt, int n_edges, int nodeBlocks) {
  int tid = threadIdx.x;

  if (blockIdx.x >= nodeBlocks) {
    // ---- hist part (scalar, R11-proven) ----
    int hb = blockIdx.x - nodeBlocks;
    int nhb = gridDim.x - nodeBlocks;
    int i = hb * blockDim.x + tid;
    int stride = nhb * blockDim.x;
    for (; i < n_edges; i += stride)
      if (dir[i] == 0) atomicAdd(&cnt[dst[i]], 1);
    return;
  }

  // ---- node MFMA part ----
  int lane = tid & 63;
  int l15 = lane & 15;
  int kg = lane >> 4;

  bf16x8 bS[4][2], bF[4][2];
#pragma unroll
  for (int q = 0; q < 4; ++q) {
#pragma unroll
    for (int h = 0; h < 2; ++h) {
      const float* ps = W_self + (size_t)(q * 16 + l15) * D + h * 32 + kg * 8;
      const float* pf = W_f + (size_t)(q * 16 + l15) * D + h * 32 + kg * 8;
      float4 s0 = *(const float4*)ps, s1 = *(const float4*)(ps + 4);
      float4 f0 = *(const float4*)pf, f1 = *(const float4*)(pf + 4);
      bf16x8 vs, vf;
      vs[0] = f2bf(s0.x); vs[1] = f2bf(s0.y); vs[2] = f2bf(s0.z); vs[3] = f2bf(s0.w);
      vs[4] = f2bf(s1.x); vs[5] = f2bf(s1.y); vs[6] = f2bf(s1.z); vs[7] = f2bf(s1.w);
      vf[0] = f2bf(f0.x); vf[1] = f2bf(f0.y); vf[2] = f2bf(f0.z); vf[3] = f2bf(f0.w);
      vf[4] = f2bf(f1.x); vf[5] = f2bf(f1.y); vf[6] = f2bf(f1.z); vf[7] = f2bf(f1.w);
      bS[q][h] = vs;
      bF[q][h] = vf;
    }
  }
  float bq[4];
#pragma unroll
  for (int q = 0; q < 4; ++q) bq[q] = bias[q * 16 + l15];

  int wave = (int)(((size_t)blockIdx.x * blockDim.x + tid) >> 6);
  int n_waves = (int)(((size_t)nodeBlocks * blockDim.x) >> 6);
  int ntiles = (n_nodes + 15) >> 4;

  for (int t = wave; t < ntiles; t += n_waves) {
    int base = t << 4;
    int arow = base + l15;
    if (arow >= n_nodes) arow = n_nodes - 1;
    const float* ap = nf + (size_t)arow * D + kg * 8;
    float4 a00 = *(const float4*)ap;
    float4 a01 = *(const float4*)(ap + 4);
    float4 a10 = *(const float4*)(ap + 32);
    float4 a11 = *(const float4*)(ap + 36);
    bf16x8 af0, af1;
    af0[0] = f2bf(a00.x); af0[1] = f2bf(a00.y); af0[2] = f2bf(a00.z); af0[3] = f2bf(a00.w);
    af0[4] = f2bf(a01.x); af0[5] = f2bf(a01.y); af0[6] = f2bf(a01.z); af0[7] = f2bf(a01.w);
    af1[0] = f2bf(a10.x); af1[1] = f2bf(a10.y); af1[2] = f2bf(a10.z); af1[3] = f2bf(a10.w);
    af1[4] = f2bf(a11.x); af1[5] = f2bf(a11.y); af1[6] = f2bf(a11.z); af1[7] = f2bf(a11.w);

    bool full = (base + 16 <= n_nodes);
#pragma unroll
    for (int q = 0; q < 4; ++q) {
      f32x4 accS = {0.f, 0.f, 0.f, 0.f};
      f32x4 accF = {0.f, 0.f, 0.f, 0.f};
      accS = __builtin_amdgcn_mfma_f32_16x16x32_bf16(af0, bS[q][0], accS, 0, 0, 0);
      accS = __builtin_amdgcn_mfma_f32_16x16x32_bf16(af1, bS[q][1], accS, 0, 0, 0);
      accF = __builtin_amdgcn_mfma_f32_16x16x32_bf16(af0, bF[q][0], accF, 0, 0, 0);
      accF = __builtin_amdgcn_mfma_f32_16x16x32_bf16(af1, bF[q][1], accF, 0, 0, 0);
      int col = q * 16 + l15;
      int row0 = base + kg * 4;
      size_t o = (size_t)row0 * D + col;
      if (full) {
#pragma unroll
        for (int r = 0; r < 4; ++r) {
          out[o + (size_t)r * D] = accS[r] + bq[q];
          X2[o + (size_t)r * D] = (unsigned short)f2bf(accF[r]);
        }
      } else {
#pragma unroll
        for (int r = 0; r < 4; ++r) {
          if (row0 + r < n_nodes) {
            out[o + (size_t)r * D] = accS[r] + bq[q];
            X2[o + (size_t)r * D] = (unsigned short)f2bf(accF[r]);
          }
        }
      }
    }
  }
}

// ---------------- scan (R11-proven two-kernel version) ----------------
__global__ __launch_bounds__(256) void k_sums(
    const int* __restrict__ cnt, int* __restrict__ sums, int n) {
  __shared__ int ws_[4];
  int b = blockIdx.x, t = threadIdx.x;
  int lane = t & 63, wave = t >> 6;
  int s = 0;
  for (int j = 0; j < 4; ++j) {
    int i = b * SCAN_CHUNK + t * 4 + j;
    if (i < n) s += cnt[i];
  }
  for (int off = 32; off; off >>= 1) s += __shfl_down(s, off);
  if (lane == 0) ws_[wave] = s;
  __syncthreads();
  if (t == 0) sums[b] = ws_[0] + ws_[1] + ws_[2] + ws_[3];
}

__global__ __launch_bounds__(256) void k_scan_chunks(
    int* __restrict__ cnt, const int* __restrict__ sums, int n) {
  __shared__ int wsum[4];
  __shared__ int off_s;
  int b = blockIdx.x, t = threadIdx.x;
  int lane = t & 63, wave = t >> 6;
  if (t < 64) {
    int v = 0;
    for (int i = t; i < b; i += 64) v += sums[i];
    for (int o = 32; o; o >>= 1) v += __shfl_down(v, o);
    if (t == 0) off_s = v;
  }
  int i0 = b * SCAN_CHUNK + t * 4;
  int c0 = (i0 + 0 < n) ? cnt[i0 + 0] : 0;
  int c1 = (i0 + 1 < n) ? cnt[i0 + 1] : 0;
  int c2 = (i0 + 2 < n) ? cnt[i0 + 2] : 0;
  int c3 = (i0 + 3 < n) ? cnt[i0 + 3] : 0;
  int s = c0 + c1 + c2 + c3;
  int inc = s;
  for (int d = 1; d < 64; d <<= 1) {
    int v = __shfl_up(inc, d);
    if (lane >= d) inc += v;
  }
  if (lane == 63) wsum[wave] = inc;
  __syncthreads();
  int wbase = 0;
  if (wave > 0) wbase += wsum[0];
  if (wave > 1) wbase += wsum[1];
  if (wave > 2) wbase += wsum[2];
  int ex = off_s + wbase + inc - s;
  if (i0 + 0 < n) cnt[i0 + 0] = ex;
  if (i0 + 1 < n) cnt[i0 + 1] = ex + c0;
  if (i0 + 2 < n) cnt[i0 + 2] = ex + c0 + c1;
  if (i0 + 3 < n) cnt[i0 + 3] = ex + c0 + c1 + c2;
}

// ---------------- scatter packed (src<<8)|etype (scalar, R11-proven)
__global__ __launch_bounds__(256) void k_scatter_packed(
    const int* __restrict__ src, const int* __restrict__ dst,
    const int* __restrict__ et, const int* __restrict__ dir,
    int* __restrict__ cursor, int* __restrict__ perm, int n_edges) {
  int i = blockIdx.x * blockDim.x + threadIdx.x;
  int stride = gridDim.x * blockDim.x;
  for (; i < n_edges; i += stride)
    if (dir[i] == 0) {
      int pos = atomicAdd(&cursor[dst[i]], 1);
      perm[pos] = (src[i] << 8) | et[i];
    }
}

// ---------------- gather: out[n] += sum_{e in bucket(n)} X2[src[e]] - R2[et[e]]
__global__ __launch_bounds__(256) void k_gather(
    const int* __restrict__ cursor, const int* __restrict__ perm,
    const unsigned short* __restrict__ X2, const unsigned short* __restrict__ R2,
    float* __restrict__ out, int n_nodes) {
  int lane = threadIdx.x & 63;
  int wave_id = (int)((blockIdx.x * blockDim.x + threadIdx.x) >> 6);
  int n_waves = (int)((gridDim.x * blockDim.x) >> 6);
  for (int node = wave_id; node < n_nodes; node += n_waves) {
    int end = cursor[node];
    int beg = (node == 0) ? 0 : cursor[node - 1];
    if (end <= beg) continue;
    float acc = 0.f;
    int k = beg;
    for (; k + 3 < end; k += 4) {
      int p0 = perm[k], p1 = perm[k + 1], p2 = perm[k + 2], p3 = perm[k + 3];
      float a0 = bf2f(X2[(size_t)(p0 >> 8) * D + lane]) - bf2f(R2[(size_t)(p0 & 255) * D + lane]);
      float a1 = bf2f(X2[(size_t)(p1 >> 8) * D + lane]) - bf2f(R2[(size_t)(p1 & 255) * D + lane]);
      float a2 = bf2f(X2[(size_t)(p2 >> 8) * D + lane]) - bf2f(R2[(size_t)(p2 & 255) * D + lane]);
      float a3 = bf2f(X2[(size_t)(p3 >> 8) * D + lane]) - bf2f(R2[(size_t)(p3 & 255) * D + lane]);
      acc += (a0 + a1) + (a2 + a3);
    }
    for (; k < end; ++k) {
      int p = perm[k];
      acc += bf2f(X2[(size_t)(p >> 8) * D + lane]) - bf2f(R2[(size_t)(p & 255) * D + lane]);
    }
    out[(size_t)node * D + lane] += acc;
  }
}

// ---------------- fallback edge kernel (atomic, bf16 X/R) ----------------
__global__ __launch_bounds__(256) void edge_atomic(
    const int* __restrict__ src, const int* __restrict__ dst,
    const int* __restrict__ et, const int* __restrict__ dir,
    const unsigned short* __restrict__ X2, const unsigned short* __restrict__ R2,
    float* __restrict__ out, int n_edges) {
  int lane = threadIdx.x & 63;
  long long wave_id = ((long long)blockIdx.x * blockDim.x + threadIdx.x) >> 6;
  long long n_waves = ((long long)gridDim.x * blockDim.x) >> 6;
  for (long long base = wave_id * 64; base < n_edges; base += n_waves * 64) {
    int e = (int)base + lane;
    int s_l = 0, d_l = 0, t_l = 0, dir_l = 1;
    if (e < n_edges) {
      s_l = src[e]; d_l = dst[e]; t_l = et[e]; dir_l = dir[e];
    }
    int cnt = min(64, n_edges - (int)base);
    for (int i = 0; i < cnt; ++i) {
      int dir_i = __shfl(dir_l, i);
      if (dir_i != 0) continue;
      int s_i = __shfl(s_l, i);
      int t_i = __shfl(t_l, i);
      int d_i = __shfl(d_l, i);
      float val = bf2f(X2[(size_t)s_i * D + lane]) - bf2f(R2[(size_t)t_i * D + lane]);
      atomicAdd(&out[(size_t)d_i * D + lane], val);
    }
  }
}

extern "C" void kernel_launch(void* const* d_in, const int* in_sizes, int n_in,
                              void* d_out, int out_size, void* d_ws, size_t ws_size,
                              hipStream_t stream) {
  const float* node_feat = (const float*)d_in[0];
  const float* rel_emb   = (const float*)d_in[1];
  const int*   src       = (const int*)d_in[2];
  const int*   dst       = (const int*)d_in[3];
  const int*   etype     = (const int*)d_in[4];
  const int*   direction = (const int*)d_in[5];
  const float* W_self    = (const float*)d_in[6];
  const float* W_forward = (const float*)d_in[7];
  // d_in[8] = W_backward (unused: backward edges contribute zero)
  const float* W_rel     = (const float*)d_in[9];
  const float* bias      = (const float*)d_in[10];

  int n_nodes = in_sizes[0] / D;
  int n_rel   = in_sizes[1] / D;
  int n_edges = in_sizes[2];

  float* out     = (float*)d_out;
  float* rel_out = out + (size_t)n_nodes * D;

  // ws layout: X2(bf16), R2(bf16), cursor, sums, perm  (R11 layout)
  char* ws = (char*)d_ws;
  size_t offX = 0;
  size_t offR = offX + (size_t)n_nodes * D * 2;
  size_t offCur = (offR + (size_t)n_rel * D * 2 + 15) & ~(size_t)15;
  size_t offSums = offCur + (((size_t)n_nodes * 4 + 15) & ~(size_t)15);
  size_t offPerm = offSums + 1024 * 4;
  size_t need = offPerm + (size_t)n_edges * 4;

  unsigned short* X2 = (unsigned short*)(ws + offX);
  unsigned short* R2 = (unsigned short*)(ws + offR);
  int* cursor = (int*)(ws + offCur);
  int* sums = (int*)(ws + offSums);
  int* perm = (int*)(ws + offPerm);

  bool packed_ok = (n_rel <= 256) && (n_nodes < (1 << 23));
  bool csr = (ws_size >= need) && packed_ok;
  int ncz4 = csr ? (n_nodes + 3) / 4 : 0;

  // 1) R2(bf16) + rel_out (+ cursor zero, folded)
  rel_kernel<<<64, 256, 0, stream>>>(rel_emb, W_forward, W_rel, R2, rel_out,
                                     n_rel, (int4*)cursor, ncz4);

  if (csr) {
    // 2) node GEMM (blocks 0..511) + hist (blocks 512..1535), fused launch
    node_hist<<<1536, 256, 0, stream>>>(node_feat, W_self, W_forward, bias,
                                        out, X2, n_nodes,
                                        dst, direction, cursor, n_edges, 512);
    int nblk = (n_nodes + SCAN_CHUNK - 1) / SCAN_CHUNK;
    k_sums<<<nblk, 256, 0, stream>>>(cursor, sums, n_nodes);
    k_scan_chunks<<<nblk, 256, 0, stream>>>(cursor, sums, n_nodes);
    k_scatter_packed<<<1024, 256, 0, stream>>>(src, dst, etype, direction,
                                               cursor, perm, n_edges);
    k_gather<<<2048, 256, 0, stream>>>(cursor, perm, X2, R2, out, n_nodes);
  } else {
    node_hist<<<512, 256, 0, stream>>>(node_feat, W_self, W_forward, bias,
                                       out, X2, n_nodes,
                                       dst, direction, cursor, 0, 512);
    edge_atomic<<<2048, 256, 0, stream>>>(src, dst, etype, direction, X2, R2,
                                          out, n_edges);
  }
}